// Round 3
// baseline (947.456 us; speedup 1.0000x reference)
//
#include <hip/hip_runtime.h>

#define DEV __device__ __forceinline__

typedef __attribute__((ext_vector_type(8))) short short8;
typedef __bf16 bf16x8 __attribute__((ext_vector_type(8)));
typedef __attribute__((ext_vector_type(4))) float f32x4;

constexpr int NB = 16;
constexpr int NN = 64;
constexpr int ND = 512;
constexpr int NH = 8;

DEV float b2f(unsigned short h) { return __uint_as_float(((unsigned)h) << 16); }
DEV unsigned short f2b(float f) {
    unsigned u = __float_as_uint(f);
    return (unsigned short)((u + 0x7fffu + ((u >> 16) & 1u)) >> 16);
}
DEV float mishf(float x) {
    float sp = (x > 20.0f) ? x : log1pf(expf(x));
    return x * tanhf(sp);
}

// ---------------------------------------------------------------------------
// dtype probe for INPUTS: adj_matrix is uniform[0,1) (positive). As f32,
// bit15 of a word is a random mantissa bit (~50% set). As packed bf16 pairs,
// bit15 is the sign of the low element -> 0. (Round-1 NaN already proved f32;
// this keeps us robust either way.)
// ---------------------------------------------------------------------------
__global__ __launch_bounds__(64)
void probe_dtype(const unsigned* __restrict__ adj, int* __restrict__ flag)
{
    int t = threadIdx.x;
    int c = 0;
#pragma unroll
    for (int i = 0; i < 4; ++i) c += (int)((adj[t * 4 + i] >> 15) & 1u);
    for (int off = 32; off; off >>= 1) c += __shfl_xor(c, off);
    if (t == 0) flag[0] = (c > 32) ? 1 : 0;
}

// ---------------------------------------------------------------------------
// Transpose the five 512x512 weights into canonical bf16: Wt[c][k] = W[k][c]
// ---------------------------------------------------------------------------
__global__ __launch_bounds__(256)
void wtrans(const void* W0, const void* W1, const void* W2, const void* W3,
            const void* W4, unsigned short* __restrict__ out,
            const int* __restrict__ flag)
{
    const void* W = (blockIdx.z == 0) ? W0 : (blockIdx.z == 1) ? W1 :
                    (blockIdx.z == 2) ? W2 : (blockIdx.z == 3) ? W3 : W4;
    const int f32 = flag[0];
    unsigned short* o = out + (size_t)blockIdx.z * 262144;
    __shared__ unsigned short tile[64][65];
    const int t = threadIdx.x;
    const int k0 = blockIdx.x * 64, c0 = blockIdx.y * 64;
#pragma unroll
    for (int rep = 0; rep < 16; ++rep) {
        int idx = rep * 256 + t;
        int r = idx >> 6, c = idx & 63;
        size_t gi = (size_t)(k0 + r) * 512 + c0 + c;
        float v = f32 ? ((const float*)W)[gi]
                      : b2f(((const unsigned short*)W)[gi]);
        tile[r][c] = f2b(v);
    }
    __syncthreads();
#pragma unroll
    for (int rep = 0; rep < 16; ++rep) {
        int idx = rep * 256 + t;
        int cc = idx >> 6, kk = idx & 63;
        o[(size_t)(c0 + cc) * 512 + k0 + kk] = tile[kk][cc];
    }
}

// ---------------------------------------------------------------------------
// GEMM: out[M x 512] = f( A[M x 512] @ W[512 x 512] + bias ), W pre-transposed
// (Bt[c][k], bf16). 64 rows x 512 cols per block (full width). 4 waves, BK=32.
// AIN:    A is a raw harness input -> dtype via flag (f32 or bf16), pitch apitch
//         (elements). Otherwise A is canonical bf16 with pitch apitch shorts.
// MSG:    A[r][c] *= msg[b, c>>6, m, n]   (r = (b*64+m)*64+n)
// MISH:   epilogue activation
// OUTF32: write f32 (pitch opitch floats); else bf16 (pitch opitch shorts).
// In-place safety (A and out aliased, strided kp/nh): each block touches only
// byte range [row*2048, +2048) of its own 64 rows; reads precede writes.
// ---------------------------------------------------------------------------
template<bool AIN, bool MSG, bool MISH, bool OUTF32>
__global__ __launch_bounds__(256)
void gemm_k512(const void* A, int apitch,
               const unsigned short* __restrict__ Bt,
               const void* __restrict__ bias,
               const float* __restrict__ msg,
               void* out, int opitch,
               const int* __restrict__ flag)
{
    __shared__ alignas(16) unsigned short As[64][40];
    __shared__ alignas(16) unsigned short Bs[512][40];
    const int f32g = flag[0];
    const int af32 = AIN ? f32g : 0;
    const int t = threadIdx.x;
    const int lane = t & 63;
    const int wm = t >> 6;
    const long long row0 = (long long)blockIdx.x * 64;

    f32x4 acc[32];
#pragma unroll
    for (int f = 0; f < 32; ++f) acc[f] = f32x4{0.f, 0.f, 0.f, 0.f};

    const int arow = t >> 2;        // 0..63
    const int akq  = (t & 3) * 8;   // 0,8,16,24
    const long long gr = row0 + arow;
    const float* mptr = nullptr;
    if (MSG) {
        int b = (int)(gr >> 12);
        int m = (int)(gr >> 6) & 63;
        int n = (int)gr & 63;
        mptr = msg + ((long long)b * 32768 + m * 64 + n);  // + h*4096
    }

    for (int kk = 0; kk < 512; kk += 32) {
        // ---- stage A tile (64 x 32) as canonical bf16 ----
        {
            long long base = gr * (long long)apitch + kk + akq;
            float av[8];
            if (af32) {
                const float* pf = (const float*)A;
                f32x4 x0 = *reinterpret_cast<const f32x4*>(pf + base);
                f32x4 x1 = *reinterpret_cast<const f32x4*>(pf + base + 4);
#pragma unroll
                for (int j = 0; j < 4; ++j) { av[j] = x0[j]; av[j + 4] = x1[j]; }
            } else {
                short8 v = *reinterpret_cast<const short8*>((const unsigned short*)A + base);
#pragma unroll
                for (int j = 0; j < 8; ++j) av[j] = b2f((unsigned short)v[j]);
            }
            if (MSG) {
                float s = mptr[((kk + akq) >> 6) * 4096];
#pragma unroll
                for (int j = 0; j < 8; ++j) av[j] *= s;
            }
            short8 sv;
#pragma unroll
            for (int j = 0; j < 8; ++j) sv[j] = (short)f2b(av[j]);
            *reinterpret_cast<short8*>(&As[arow][akq]) = sv;
        }
        // ---- stage W tile (512 cols x 32 k) ----
#pragma unroll
        for (int rep = 0; rep < 8; ++rep) {
            int idx = rep * 256 + t;
            int col = idx >> 2;
            int kq = (idx & 3) * 8;
            *reinterpret_cast<short8*>(&Bs[col][kq]) =
                *reinterpret_cast<const short8*>(Bt + (long long)col * 512 + kk + kq);
        }
        __syncthreads();
        bf16x8 a = *reinterpret_cast<const bf16x8*>(&As[wm * 16 + (lane & 15)][(lane >> 4) * 8]);
#pragma unroll
        for (int f = 0; f < 32; ++f) {
            bf16x8 b = *reinterpret_cast<const bf16x8*>(&Bs[f * 16 + (lane & 15)][(lane >> 4) * 8]);
            acc[f] = __builtin_amdgcn_mfma_f32_16x16x32_bf16(a, b, acc[f], 0, 0, 0);
        }
        __syncthreads();
    }

    // epilogue: C/D layout col=lane&15, row=(lane>>4)*4+r
    const int orow = wm * 16 + (lane >> 4) * 4;
#pragma unroll
    for (int f = 0; f < 32; ++f) {
        int col = f * 16 + (lane & 15);
        float bz = f32g ? ((const float*)bias)[col]
                        : b2f(((const unsigned short*)bias)[col]);
#pragma unroll
        for (int r = 0; r < 4; ++r) {
            float v2 = acc[f][r] + bz;
            if (MISH) v2 = mishf(v2);
            long long oi = (row0 + orow + r) * (long long)opitch + col;
            if (OUTF32) ((float*)out)[oi] = v2;
            else        ((unsigned short*)out)[oi] = f2b(v2);
        }
    }
}

// ---------------------------------------------------------------------------
// message kernel: one wave per (b,h,i) row; q bf16 (pitch 512), kp bf16
// strided (pitch 1024 shorts).
// lane j: out_score = q[i]·kp[b,i,j,h,:]/8 ; in_score = q[i]·kp[b,j,i,h,:]/8
// msg[i][j] = out_attn + in_attn, except msg[i][i] = in_attn[i][i].
// ---------------------------------------------------------------------------
__global__ __launch_bounds__(64)
void msg_kernel(const unsigned short* __restrict__ q,
                const unsigned short* __restrict__ kp,
                float* __restrict__ msg)
{
    const int bid = blockIdx.x;
    const int i = bid & 63;
    const int h = (bid >> 6) & 7;
    const int b = bid >> 9;
    const int l = threadIdx.x;
    __shared__ float qs[64];
    qs[l] = b2f(q[((long long)(b * 64 + i)) * 512 + h * 64 + l]);
    __syncthreads();
    const unsigned short* ko = kp + (((long long)(b * 64 + i)) * 64 + l) * 1024 + h * 64;
    const unsigned short* ki = kp + (((long long)(b * 64 + l)) * 64 + i) * 1024 + h * 64;
    float so = 0.f, si = 0.f;
#pragma unroll
    for (int d8 = 0; d8 < 8; ++d8) {
        short8 vo = *reinterpret_cast<const short8*>(ko + d8 * 8);
        short8 vi = *reinterpret_cast<const short8*>(ki + d8 * 8);
#pragma unroll
        for (int j = 0; j < 8; ++j) {
            float qv = qs[d8 * 8 + j];
            so += qv * b2f((unsigned short)vo[j]);
            si += qv * b2f((unsigned short)vi[j]);
        }
    }
    so *= 0.125f; si *= 0.125f;
    float mo = so, mi = si;
    for (int off = 32; off; off >>= 1) {
        mo = fmaxf(mo, __shfl_xor(mo, off));
        mi = fmaxf(mi, __shfl_xor(mi, off));
    }
    float eo = expf(so - mo), ei = expf(si - mi);
    float zo = eo, zi = ei;
    for (int off = 32; off; off >>= 1) {
        zo += __shfl_xor(zo, off);
        zi += __shfl_xor(zi, off);
    }
    float ao = eo / zo, ai = ei / zi;
    msg[(long long)bid * 64 + l] = (l == i) ? ai : (ao + ai);
}

// ---------------------------------------------------------------------------
// node_hidden[b,m,c] = sum_n msg[b, c>>6, m, n] * v[b,n,c]
// writes bf16 STRIDED (pitch 1024 shorts) into the node f32 output region.
// ---------------------------------------------------------------------------
__global__ __launch_bounds__(512)
void nh_kernel(const float* __restrict__ msg,
               const unsigned short* __restrict__ v,
               unsigned short* __restrict__ nh)
{
    const int bm = blockIdx.x;
    const int b = bm >> 6, m = bm & 63;
    const int t = threadIdx.x;  // 0..511
    __shared__ float ms[8 * 64];
    ms[t] = msg[((long long)b * 8 + (t >> 6)) * 4096 + m * 64 + (t & 63)];
    __syncthreads();
    const float* mrow = &ms[(t >> 6) * 64];
    float acc = 0.f;
#pragma unroll 8
    for (int n = 0; n < 64; ++n)
        acc += mrow[n] * b2f(v[((long long)b * 64 + n) * 512 + t]);
    nh[(long long)bm * 1024 + t] = f2b(acc);
}

// ---------------------------------------------------------------------------
extern "C" void kernel_launch(void* const* d_in, const int* in_sizes, int n_in,
                              void* d_out, int out_size, void* d_ws, size_t ws_size,
                              hipStream_t stream)
{
    const void* qn = d_in[0];
    const void* vn = d_in[1];
    const void* ke = d_in[2];
    const unsigned* adj = (const unsigned*)d_in[3];  // dtype probe only
    const void* Wq = d_in[4];  const void* bq = d_in[5];
    const void* Wk = d_in[6];  const void* bk = d_in[7];
    const void* Wv = d_in[8];  const void* bv = d_in[9];
    const void* Wn = d_in[10]; const void* bn = d_in[11];
    const void* We = d_in[12]; const void* be = d_in[13];

    float* out_node = (float*)d_out;                       // 16*64*512 f32
    float* out_edge = out_node + (size_t)NB * NN * ND;     // 16*64*64*512 f32
    // strided bf16 scratch aliased into the f32 output regions:
    // row r occupies shorts [r*1024, r*1024+512) == bytes [r*2048, +1024),
    // the same byte range its f32 output row later overwrites.
    unsigned short* kp = (unsigned short*)out_edge;        // pitch 1024 shorts
    unsigned short* nh = (unsigned short*)out_node;        // pitch 1024 shorts

    char* wsb = (char*)d_ws;
    int* flag = (int*)wsb;
    unsigned short* Wt  = (unsigned short*)(wsb + 16);     // 5 x 512 KB
    unsigned short* Wqt = Wt + 0 * 262144;
    unsigned short* Wkt = Wt + 1 * 262144;
    unsigned short* Wvt = Wt + 2 * 262144;
    unsigned short* Wnt = Wt + 3 * 262144;
    unsigned short* Wet = Wt + 4 * 262144;
    unsigned short* q_ws = Wt + 5 * 262144;                // 1 MB bf16
    unsigned short* v_ws = q_ws + 524288;                  // 1 MB bf16
    float* msg = (float*)(v_ws + 524288);                  // 2 MB f32
    // ws total ~6.5 MB

    probe_dtype<<<1, 64, 0, stream>>>(adj, flag);
    wtrans<<<dim3(8, 8, 5), 256, 0, stream>>>(Wq, Wk, Wv, Wn, We, Wt, flag);
    // projections: A = raw f32 inputs (pitch 512), bf16 outputs
    gemm_k512<true, false, false, false><<<16,   256, 0, stream>>>(qn, 512, Wqt, bq, nullptr, q_ws, 512, flag);
    gemm_k512<true, false, false, false><<<16,   256, 0, stream>>>(vn, 512, Wvt, bv, nullptr, v_ws, 512, flag);
    // k projection -> strided bf16 inside the edge f32 output region
    gemm_k512<true, false, false, false><<<1024, 256, 0, stream>>>(ke, 512, Wkt, bk, nullptr, kp, 1024, flag);
    // attention message
    msg_kernel<<<NB * NH * NN, 64, 0, stream>>>(q_ws, kp, msg);
    // node path: nh strided into node region, then in-place f32 GEMM + mish
    nh_kernel<<<NB * NN, 512, 0, stream>>>(msg, v_ws, nh);
    gemm_k512<false, false, true, true><<<16,   256, 0, stream>>>(nh, 1024, Wnt, bn, nullptr, out_node, 512, flag);
    // edge path: A = kp (strided, scaled by msg on the fly), in-place f32 + mish
    gemm_k512<false, true,  true, true><<<1024, 256, 0, stream>>>(kp, 1024, Wet, be, msg, out_edge, 512, flag);
}

// Round 4
// 415.893 us; speedup vs baseline: 2.2781x; 2.2781x over previous
//
#include <hip/hip_runtime.h>

#define DEV __device__ __forceinline__

typedef __attribute__((ext_vector_type(8))) short short8;
typedef __bf16 bf16x8 __attribute__((ext_vector_type(8)));
typedef __attribute__((ext_vector_type(4))) float f32x4;

constexpr int NB = 16;
constexpr int NN = 64;
constexpr int ND = 512;
constexpr int NH = 8;

DEV float b2f(unsigned short h) { return __uint_as_float(((unsigned)h) << 16); }
DEV unsigned short f2b(float f) {
    unsigned u = __float_as_uint(f);
    return (unsigned short)((u + 0x7fffu + ((u >> 16) & 1u)) >> 16);
}
// mish(x) = x*tanh(softplus(x)) = x*(t^2+2t)/(t^2+2t+2), t=e^x; x>15 -> x
DEV float mish_fast(float x) {
    float t = __expf(x);
    float w = t * (t + 2.0f);
    float r = x * w * __builtin_amdgcn_rcpf(w + 2.0f);
    return (x > 15.0f) ? x : r;
}
DEV void gload16(const unsigned short* g, unsigned short* lds) {
    __builtin_amdgcn_global_load_lds((const __attribute__((address_space(1))) void*)g,
                                     (__attribute__((address_space(3))) void*)lds,
                                     16, 0, 0);
}

// ---------------------------------------------------------------------------
// dtype probe (inputs are f32 per round-1/2 evidence; keep dynamic anyway)
// ---------------------------------------------------------------------------
__global__ __launch_bounds__(64)
void probe_dtype(const unsigned* __restrict__ adj, int* __restrict__ flag)
{
    int t = threadIdx.x;
    int c = 0;
#pragma unroll
    for (int i = 0; i < 4; ++i) c += (int)((adj[t * 4 + i] >> 15) & 1u);
    for (int off = 32; off; off >>= 1) c += __shfl_xor(c, off);
    if (t == 0) flag[0] = (c > 32) ? 1 : 0;
}

// ---------------------------------------------------------------------------
// Transpose the five 512x512 weights into canonical bf16: Wt[c][k] = W[k][c]
// ---------------------------------------------------------------------------
__global__ __launch_bounds__(256)
void wtrans(const void* W0, const void* W1, const void* W2, const void* W3,
            const void* W4, unsigned short* __restrict__ out,
            const int* __restrict__ flag)
{
    const void* W = (blockIdx.z == 0) ? W0 : (blockIdx.z == 1) ? W1 :
                    (blockIdx.z == 2) ? W2 : (blockIdx.z == 3) ? W3 : W4;
    const int f32 = flag[0];
    unsigned short* o = out + (size_t)blockIdx.z * 262144;
    __shared__ unsigned short tile[64][65];
    const int t = threadIdx.x;
    const int k0 = blockIdx.x * 64, c0 = blockIdx.y * 64;
#pragma unroll
    for (int rep = 0; rep < 16; ++rep) {
        int idx = rep * 256 + t;
        int r = idx >> 6, c = idx & 63;
        size_t gi = (size_t)(k0 + r) * 512 + c0 + c;
        float v = f32 ? ((const float*)W)[gi]
                      : b2f(((const unsigned short*)W)[gi]);
        tile[r][c] = f2b(v);
    }
    __syncthreads();
#pragma unroll
    for (int rep = 0; rep < 16; ++rep) {
        int idx = rep * 256 + t;
        int cc = idx >> 6, kk = idx & 63;
        o[(size_t)(c0 + cc) * 512 + k0 + kk] = tile[kk][cc];
    }
}

// ---------------------------------------------------------------------------
// GEMM v2: out[64 x 512 per block] = f( A[64 x 512] @ W + bias )
// A-panel fully LDS-resident (staged once, XOR-swizzled granules);
// B-tile (256 cols x 32 k) staged per K-step via global_load_lds.
// 4 waves; wave w covers cols [w*64, w*64+64) of the current 256-col panel
// with a 4x4 grid of 16x16x32 MFMA fragments.
// As slot (r,s) holds granule s^(r&7) of row r   (granule = 8 bf16 = 16 B)
// Bs slot (c,s) holds granule s^((c>>1)&3) of col c
// AF32: A is a raw input (dtype via flag), reg-converted; else bf16 via gload.
// Aliased GEMMs (A and out overlap) MUST launch gridDim.y=1: A is fully in
// LDS before the first output write; col-panels sequential within the block.
// ---------------------------------------------------------------------------
template<bool AF32, bool MISH, bool OUTF32>
__global__ __launch_bounds__(256, 2)
void gemm2(const void* A, int apitch,
           const unsigned short* __restrict__ Bt,
           const void* __restrict__ bias_raw,
           void* out, int opitch,
           const int* __restrict__ flag)
{
    __shared__ alignas(16) unsigned short As[64][512];   // 64 KB
    __shared__ alignas(16) unsigned short Bs[256][32];   // 16 KB
    const int f32g = flag[0];
    const int t = threadIdx.x;
    const int lane = t & 63;
    const int wv = t >> 6;
    const long long row0 = (long long)blockIdx.x * 64;

    // ---- stage the whole A panel (64 x 512) ----
    if (AF32) {
        if (f32g) {
            const float* Af = (const float*)A;
#pragma unroll
            for (int i = 0; i < 16; ++i) {
                int fl = i * 256 + t;
                int r = fl >> 6, s = fl & 63;
                int d = s ^ (r & 7);
                const float* src = Af + (row0 + r) * (long long)apitch + d * 8;
                f32x4 x0 = *reinterpret_cast<const f32x4*>(src);
                f32x4 x1 = *reinterpret_cast<const f32x4*>(src + 4);
                short8 sv;
#pragma unroll
                for (int j = 0; j < 4; ++j) { sv[j] = (short)f2b(x0[j]); sv[j + 4] = (short)f2b(x1[j]); }
                *reinterpret_cast<short8*>(&As[r][s * 8]) = sv;
            }
        } else {
            const unsigned short* Ah = (const unsigned short*)A;
#pragma unroll
            for (int i = 0; i < 16; ++i) {
                int fl = i * 256 + t;
                int r = fl >> 6, s = fl & 63;
                int d = s ^ (r & 7);
                *reinterpret_cast<short8*>(&As[r][s * 8]) =
                    *reinterpret_cast<const short8*>(Ah + (row0 + r) * (long long)apitch + d * 8);
            }
        }
    } else {
        const unsigned short* Ah = (const unsigned short*)A;
#pragma unroll
        for (int i = 0; i < 16; ++i) {
            int r = wv * 16 + i;
            const unsigned short* src = Ah + (row0 + r) * (long long)apitch + ((lane ^ (r & 7)) << 3);
            gload16(src, &As[r][0]);   // wave-uniform LDS base; lane*16B implicit
        }
    }

    const int p  = lane >> 4;    // k-granule 0..3 within the 32-k tile
    const int rA = lane & 15;

    for (int cp = blockIdx.y; cp < 2; cp += gridDim.y) {
        f32x4 acc[4][4];
#pragma unroll
        for (int mi = 0; mi < 4; ++mi)
#pragma unroll
            for (int ni = 0; ni < 4; ++ni) acc[mi][ni] = f32x4{0.f, 0.f, 0.f, 0.f};

        for (int kk = 0; kk < 16; ++kk) {
            // stage B tile: cols [cp*256, +256) x k [kk*32, +32)
#pragma unroll
            for (int j = 0; j < 4; ++j) {
                int colb = wv * 64 + j * 16;
                int cl = colb + (lane >> 2);
                int d2 = (lane & 3) ^ ((cl >> 1) & 3);
                const unsigned short* src =
                    Bt + (size_t)(cp * 256 + cl) * 512 + kk * 32 + d2 * 8;
                gload16(src, &Bs[colb][0]);
            }
            __syncthreads();   // drains vmem (A on first iter; B this iter)

            bf16x8 af[4], bfr[4];
#pragma unroll
            for (int mi = 0; mi < 4; ++mi) {
                int r = mi * 16 + rA;
                int s = ((kk << 2) | p) ^ (r & 7);
                af[mi] = *reinterpret_cast<const bf16x8*>(&As[r][s * 8]);
            }
#pragma unroll
            for (int ni = 0; ni < 4; ++ni) {
                int c = wv * 64 + ni * 16 + rA;
                int s2 = p ^ ((c >> 1) & 3);
                bfr[ni] = *reinterpret_cast<const bf16x8*>(&Bs[c][s2 * 8]);
            }
#pragma unroll
            for (int mi = 0; mi < 4; ++mi)
#pragma unroll
                for (int ni = 0; ni < 4; ++ni)
                    acc[mi][ni] = __builtin_amdgcn_mfma_f32_16x16x32_bf16(af[mi], bfr[ni], acc[mi][ni], 0, 0, 0);
            __syncthreads();   // all reads done before next overwrite
        }

        // epilogue: C/D layout col=lane&15, row=(lane>>4)*4+rr
        const int orow_q = (lane >> 4) * 4;
#pragma unroll
        for (int mi = 0; mi < 4; ++mi) {
#pragma unroll
            for (int ni = 0; ni < 4; ++ni) {
                int col = cp * 256 + wv * 64 + ni * 16 + rA;
                float bz = f32g ? ((const float*)bias_raw)[col]
                                : b2f(((const unsigned short*)bias_raw)[col]);
                long long rbase = row0 + mi * 16 + orow_q;
#pragma unroll
                for (int rr = 0; rr < 4; ++rr) {
                    float v = acc[mi][ni][rr] + bz;
                    if (MISH) v = mish_fast(v);
                    long long oi = (rbase + rr) * (long long)opitch + col;
                    if (OUTF32) ((float*)out)[oi] = v;
                    else        ((unsigned short*)out)[oi] = f2b(v);
                }
            }
        }
    }
}

// ---------------------------------------------------------------------------
// message kernel: one wave per (b,h,i) row (unchanged, verified round 3)
// ---------------------------------------------------------------------------
__global__ __launch_bounds__(64)
void msg_kernel(const unsigned short* __restrict__ q,
                const unsigned short* __restrict__ kp,
                float* __restrict__ msg)
{
    const int bid = blockIdx.x;
    const int i = bid & 63;
    const int h = (bid >> 6) & 7;
    const int b = bid >> 9;
    const int l = threadIdx.x;
    __shared__ float qs[64];
    qs[l] = b2f(q[((long long)(b * 64 + i)) * 512 + h * 64 + l]);
    __syncthreads();
    const unsigned short* ko = kp + (((long long)(b * 64 + i)) * 64 + l) * 1024 + h * 64;
    const unsigned short* ki = kp + (((long long)(b * 64 + l)) * 64 + i) * 1024 + h * 64;
    float so = 0.f, si = 0.f;
#pragma unroll
    for (int d8 = 0; d8 < 8; ++d8) {
        short8 vo = *reinterpret_cast<const short8*>(ko + d8 * 8);
        short8 vi = *reinterpret_cast<const short8*>(ki + d8 * 8);
#pragma unroll
        for (int j = 0; j < 8; ++j) {
            float qv = qs[d8 * 8 + j];
            so += qv * b2f((unsigned short)vo[j]);
            si += qv * b2f((unsigned short)vi[j]);
        }
    }
    so *= 0.125f; si *= 0.125f;
    float mo = so, mi = si;
    for (int off = 32; off; off >>= 1) {
        mo = fmaxf(mo, __shfl_xor(mo, off));
        mi = fmaxf(mi, __shfl_xor(mi, off));
    }
    float eo = expf(so - mo), ei = expf(si - mi);
    float zo = eo, zi = ei;
    for (int off = 32; off; off >>= 1) {
        zo += __shfl_xor(zo, off);
        zi += __shfl_xor(zi, off);
    }
    float ao = eo / zo, ai = ei / zi;
    msg[(long long)bid * 64 + l] = (l == i) ? ai : (ao + ai);
}

// ---------------------------------------------------------------------------
// scale kp in place: kp[r][k] *= msg[b, k>>6, m, n]   (r = (b*64+m)*64+n)
// one 8-elem granule per thread; row-contiguous, coalesced
// ---------------------------------------------------------------------------
__global__ __launch_bounds__(256)
void scale_kp(unsigned short* kp, const float* __restrict__ msg)
{
    int id = blockIdx.x * 256 + threadIdx.x;   // granule id (8 shorts)
    int r = id >> 6;
    int k8 = id & 63;
    int b = r >> 12, m = (r >> 6) & 63, n = r & 63;
    float s = msg[(((long long)b * 8 + (k8 >> 3)) << 12) + m * 64 + n];
    unsigned short* ptr = kp + (long long)r * 1024 + k8 * 8;
    short8 v = *reinterpret_cast<short8*>(ptr);
#pragma unroll
    for (int j = 0; j < 8; ++j) v[j] = (short)f2b(b2f((unsigned short)v[j]) * s);
    *reinterpret_cast<short8*>(ptr) = v;
}

// ---------------------------------------------------------------------------
// node_hidden[b,m,c] = sum_n msg[b, c>>6, m, n] * v[b,n,c]  (strided bf16 out)
// ---------------------------------------------------------------------------
__global__ __launch_bounds__(512)
void nh_kernel(const float* __restrict__ msg,
               const unsigned short* __restrict__ v,
               unsigned short* __restrict__ nh)
{
    const int bm = blockIdx.x;
    const int b = bm >> 6, m = bm & 63;
    const int t = threadIdx.x;
    __shared__ float ms[8 * 64];
    ms[t] = msg[((long long)b * 8 + (t >> 6)) * 4096 + m * 64 + (t & 63)];
    __syncthreads();
    const float* mrow = &ms[(t >> 6) * 64];
    float acc = 0.f;
#pragma unroll 8
    for (int n = 0; n < 64; ++n)
        acc += mrow[n] * b2f(v[((long long)b * 64 + n) * 512 + t]);
    nh[(long long)bm * 1024 + t] = f2b(acc);
}

// ---------------------------------------------------------------------------
extern "C" void kernel_launch(void* const* d_in, const int* in_sizes, int n_in,
                              void* d_out, int out_size, void* d_ws, size_t ws_size,
                              hipStream_t stream)
{
    const void* qn = d_in[0];
    const void* vn = d_in[1];
    const void* ke = d_in[2];
    const unsigned* adj = (const unsigned*)d_in[3];
    const void* Wq = d_in[4];  const void* bq = d_in[5];
    const void* Wk = d_in[6];  const void* bk = d_in[7];
    const void* Wv = d_in[8];  const void* bv = d_in[9];
    const void* Wn = d_in[10]; const void* bn = d_in[11];
    const void* We = d_in[12]; const void* be = d_in[13];

    float* out_node = (float*)d_out;                       // 16*64*512 f32
    float* out_edge = out_node + (size_t)NB * NN * ND;     // 16*64*64*512 f32
    // strided bf16 scratch aliased into the f32 output regions: row r's bf16
    // occupies bytes [r*2048, +1024) — same rows its f32 output later covers.
    unsigned short* kp = (unsigned short*)out_edge;        // pitch 1024 shorts
    unsigned short* nh = (unsigned short*)out_node;        // pitch 1024 shorts

    char* wsb = (char*)d_ws;
    int* flag = (int*)wsb;
    unsigned short* Wt  = (unsigned short*)(wsb + 16);     // 5 x 512 KB
    unsigned short* Wqt = Wt + 0 * 262144;
    unsigned short* Wkt = Wt + 1 * 262144;
    unsigned short* Wvt = Wt + 2 * 262144;
    unsigned short* Wnt = Wt + 3 * 262144;
    unsigned short* Wet = Wt + 4 * 262144;
    unsigned short* q_ws = Wt + 5 * 262144;                // 1 MB bf16
    unsigned short* v_ws = q_ws + 524288;                  // 1 MB bf16
    float* msg = (float*)(v_ws + 524288);                  // 2 MB f32
    // ws total ~6.5 MB

    probe_dtype<<<1, 64, 0, stream>>>(adj, flag);
    wtrans<<<dim3(8, 8, 5), 256, 0, stream>>>(Wq, Wk, Wv, Wn, We, Wt, flag);
    // projections (f32 A, reg-staged). No aliasing -> both col-panels parallel.
    gemm2<true, false, false><<<dim3(16, 2),   256, 0, stream>>>(qn, 512, Wqt, bq, q_ws, 512, flag);
    gemm2<true, false, false><<<dim3(16, 2),   256, 0, stream>>>(vn, 512, Wvt, bv, v_ws, 512, flag);
    gemm2<true, false, false><<<dim3(1024, 2), 256, 0, stream>>>(ke, 512, Wkt, bk, kp, 1024, flag);
    // attention message (reads UNscaled kp)
    msg_kernel<<<NB * NH * NN, 64, 0, stream>>>(q_ws, kp, msg);
    // fold message into kp (in place), freeing the edge GEMM of per-frag scaling
    scale_kp<<<16384, 256, 0, stream>>>(kp, msg);
    // node path
    nh_kernel<<<NB * NN, 512, 0, stream>>>(msg, v_ws, nh);
    // aliased in-place GEMMs: gridDim.y = 1 (A fully in LDS before any write)
    gemm2<false, true, true><<<dim3(16, 1),   256, 0, stream>>>(nh, 1024, Wnt, bn, out_node, 512, flag);
    gemm2<false, true, true><<<dim3(1024, 1), 256, 0, stream>>>(kp, 1024, Wet, be, out_edge, 512, flag);
}